// Round 1
// baseline (1889.961 us; speedup 1.0000x reference)
//
#include <hip/hip_runtime.h>
#include <math.h>

// Problem constants
#define BB 512
#define NN 10020
#define LL 20
#define SS 10
#define HH 1001   // (NN-LL)/SS + 1
#define INV_SQRT6 0.40824829046386296f

// Output layout (flat float offsets, in return order)
#define SZ_REC  (BB*NN*3)        // 15,390,720 reconstructed (B,N,3)
#define SZ_BH3  (BB*HH*3)        //  1,537,536 P / p1 / p2 (B,H,3)
#define SZ_ST   (BB*LL*HH*3)     // 30,750,720 st (B,L,H,3)
#define SZ_ROT  (BB*HH*LL*3)     // 30,750,720 rot_axes (B*H*L,3)
#define SZ_NH   (NN*HH)          // 10,030,020 nw / contribution (N,H)
#define O_REC   0
#define O_P     (O_REC + SZ_REC)
#define O_P1    (O_P   + SZ_BH3)
#define O_P2    (O_P1  + SZ_BH3)
#define O_ST    (O_P2  + SZ_BH3)
#define O_ROT   (O_ST  + SZ_ST)
#define O_NW    (O_ROT + SZ_ROT)
#define O_CT    (O_NW  + SZ_NH)

// --- K0: sincos table for the 20020 angles -------------------------------
__global__ void k_tab(const float* __restrict__ ang, float2* __restrict__ tab, int n) {
    int t = blockIdx.x * blockDim.x + threadIdx.x;
    if (t < n) {
        float a = ang[t];
        tab[t] = make_float2(cosf(a), sinf(a));
    }
}

// --- K1: nw (normalized) + contribution, one block per row i -------------
__global__ void __launch_bounds__(256) k_nwc(const float* __restrict__ W_enc,
                                             float* __restrict__ nw,
                                             float* __restrict__ ct) {
    int i = blockIdx.x;
    // started[i] = ceil((i+1)/S), overridden to started[N-L] for i >= N-L
    int started = (i >= NN - LL) ? ((NN - LL + SS) / SS) : ((i + SS) / SS);
    // ended[i] = max(ceil((i+1-L)/S), 0)
    int ended = (i >= LL) ? ((i - LL + SS) / SS) : 0;
    // valid h range: ended .. min(H-1, i/S); within it contribution==1
    int hhi = i / SS; if (hhi > HH - 1) hhi = HH - 1;
    float denom = 0.f;
    for (int hp = ended; hp <= hhi; ++hp)
        denom += W_enc[(size_t)((i - SS * hp) * HH + hp) * 3];
    size_t row = (size_t)i * HH;
    for (int h = threadIdx.x; h < HH; h += 256) {
        int shift = i - SS * h;
        bool valid = (shift >= 0) && (shift < LL);
        ct[row + h] = (h >= ended && h < started) ? 1.0f : 0.0f;
        nw[row + h] = valid ? W_enc[(size_t)(shift * HH + h) * 3] / denom : 0.0f;
    }
}

// --- K2: main per-(b,h) kernel -------------------------------------------
__global__ void __launch_bounds__(256) k_main(
    const float*  __restrict__ x,       const float* __restrict__ W_enc,
    const float*  __restrict__ W_dec,   const float* __restrict__ ang,
    const float2* __restrict__ tab,     const float* __restrict__ scaling,
    const float*  __restrict__ nw,
    float* __restrict__ recon, float* __restrict__ Pout,
    float* __restrict__ p1out, float* __restrict__ p2out,
    float* __restrict__ stout, float* __restrict__ rotout) {

    int tid = blockIdx.x * blockDim.x + threadIdx.x;
    if (tid >= BB * HH) return;
    int h = tid % HH;   // fastest across lanes -> coalesced h-major writes
    int b = tid / HH;

    // emb[l][k] = sum_i x[b,10h+i,k] * W_enc[i,h,l]; also emit st
    const float* xb = x + ((size_t)b * NN + (size_t)SS * h) * 3;
    float e00=0,e01=0,e02=0, e10=0,e11=0,e12=0, e20=0,e21=0,e22=0;
#pragma unroll
    for (int i = 0; i < LL; ++i) {
        float v0 = xb[i*3+0], v1 = xb[i*3+1], v2 = xb[i*3+2];
        size_t so = (((size_t)b * LL + i) * HH + h) * 3;
        stout[so+0] = v0; stout[so+1] = v1; stout[so+2] = v2;
        const float* we = W_enc + ((size_t)i * HH + h) * 3;
        float w0 = we[0], w1 = we[1], w2 = we[2];
        e00 = fmaf(v0, w0, e00); e01 = fmaf(v1, w0, e01); e02 = fmaf(v2, w0, e02);
        e10 = fmaf(v0, w1, e10); e11 = fmaf(v1, w1, e11); e12 = fmaf(v2, w1, e12);
        e20 = fmaf(v0, w2, e20); e21 = fmaf(v1, w2, e21); e22 = fmaf(v2, w2, e22);
    }
    float Px = e00, Py = e01, Pz = e02;
    float d1x = e10-Px, d1y = e11-Py, d1z = e12-Pz;
    float d2x = e20-Px, d2y = e21-Py, d2z = e22-Pz;
    float n1 = sqrtf(d1x*d1x + d1y*d1y + d1z*d1z); if (n1 == 0.f) n1 = 1.f;
    float n2 = sqrtf(d2x*d2x + d2y*d2y + d2z*d2z); if (n2 == 0.f) n2 = 1.f;
    float p1x = d1x/n1, p1y = d1y/n1, p1z = d1z/n1;
    float p2x = d2x/n2, p2y = d2y/n2, p2z = d2z/n2;
    float cx = (p1y*p2z - p1z*p2y) * INV_SQRT6;
    float cy = (p1z*p2x - p1x*p2z) * INV_SQRT6;
    float cz = (p1x*p2y - p1y*p2x) * INV_SQRT6;

    size_t bh = (size_t)b * HH + h;
    Pout [bh*3+0]=Px;  Pout [bh*3+1]=Py;  Pout [bh*3+2]=Pz;
    p1out[bh*3+0]=p1x; p1out[bh*3+1]=p1y; p1out[bh*3+2]=p1z;
    p2out[bh*3+0]=p2x; p2out[bh*3+1]=p2y; p2out[bh*3+2]=p2z;

    const float* wd0 = W_dec + (size_t)h * LL;          // W_dec[0,h,l]
    const float* wd1 = wd0 + (size_t)HH * LL;           // W_dec[1,h,l]
    const float* wd2 = wd1 + (size_t)HH * LL;           // W_dec[2,h,l]
    float ra[3*LL];
    float* rp = recon + ((size_t)b * NN + (size_t)SS * h) * 3;
#pragma unroll
    for (int l = 0; l < LL; ++l) {
        float w0 = wd0[l], w1 = wd1[l], w2 = wd2[l];
        float r0 = p1x*w0 + p2x*w1 + cx*w2;
        float r1 = p1y*w0 + p2y*w1 + cy*w2;
        float r2 = p1z*w0 + p2z*w1 + cz*w2;
        ra[l*3+0]=r0; ra[l*3+1]=r1; ra[l*3+2]=r2;
        float ca, sa;
        if (tab) { float2 cs = tab[h*LL + l]; ca = cs.x; sa = cs.y; }
        else     { float a = ang[h*LL + l];   ca = cosf(a); sa = sinf(a); }
        // q = (ca, sa*r); rotate v=p1: v' = (w^2-|r|^2)v + 2(r.v)r + 2w(r x v)
        float qx = sa*r0, qy = sa*r1, qz = sa*r2;
        float t  = ca*ca - (qx*qx + qy*qy + qz*qz);
        float rv = qx*p1x + qy*p1y + qz*p1z;
        float axv = qy*p1z - qz*p1y;
        float ayv = qz*p1x - qx*p1z;
        float azv = qx*p1y - qy*p1x;
        float v30 = t*p1x + 2.f*(rv*qx + ca*axv);
        float v31 = t*p1y + 2.f*(rv*qy + ca*ayv);
        float v32 = t*p1z + 2.f*(rv*qz + ca*azv);
        float sc  = scaling[SS*h + l];
        float g   = nw[(size_t)(SS*h + l) * HH + h];
        atomicAdd(rp + l*3 + 0, (sc*v30 + Px) * g);
        atomicAdd(rp + l*3 + 1, (sc*v31 + Py) * g);
        atomicAdd(rp + l*3 + 2, (sc*v32 + Pz) * g);
    }
    // rot_axes: 60 contiguous floats per (b,h), 240B-aligned -> float4 stores
    float4* ro4 = (float4*)(rotout + bh * (size_t)(LL*3));
#pragma unroll
    for (int t4 = 0; t4 < (3*LL)/4; ++t4)
        ro4[t4] = make_float4(ra[4*t4+0], ra[4*t4+1], ra[4*t4+2], ra[4*t4+3]);
}

extern "C" void kernel_launch(void* const* d_in, const int* in_sizes, int n_in,
                              void* d_out, int out_size, void* d_ws, size_t ws_size,
                              hipStream_t stream) {
    const float* x       = (const float*)d_in[0];
    const float* W_enc   = (const float*)d_in[1];
    const float* W_dec   = (const float*)d_in[2];
    const float* ang     = (const float*)d_in[3];
    const float* scaling = (const float*)d_in[4];
    float* out = (float*)d_out;

    float2* tab = nullptr;
    size_t tabBytes = (size_t)HH * LL * sizeof(float2);
    if (ws_size >= tabBytes) tab = (float2*)d_ws;

    // reconstructed is accumulated with atomics -> zero it (d_out is poisoned)
    hipMemsetAsync(out + O_REC, 0, (size_t)SZ_REC * sizeof(float), stream);

    if (tab)
        k_tab<<<(HH*LL + 255)/256, 256, 0, stream>>>(ang, tab, HH*LL);

    k_nwc<<<NN, 256, 0, stream>>>(W_enc, out + O_NW, out + O_CT);

    int threads = BB * HH;
    k_main<<<(threads + 255)/256, 256, 0, stream>>>(
        x, W_enc, W_dec, ang, tab, scaling, out + O_NW,
        out + O_REC, out + O_P, out + O_P1, out + O_P2, out + O_ST, out + O_ROT);
}

// Round 2
// 585.456 us; speedup vs baseline: 3.2282x; 3.2282x over previous
//
#include <hip/hip_runtime.h>
#include <math.h>

// Problem constants
#define BB 512
#define NN 10020
#define LL 20
#define SS 10
#define HH 1001   // (NN-LL)/SS + 1
#define HL (HH*LL)
#define INV_SQRT6 0.40824829046386296f
#define TPB 256
#define NT 4      // ceil(HH / TPB)

// Output layout (flat float offsets, in return order)
#define SZ_REC  (BB*NN*3)
#define SZ_BH3  (BB*HH*3)
#define SZ_ST   (BB*LL*HH*3)
#define SZ_ROT  (BB*HH*LL*3)
#define SZ_NH   (NN*HH)
#define O_REC   0
#define O_P     (O_REC + SZ_REC)
#define O_P1    (O_P   + SZ_BH3)
#define O_P2    (O_P1  + SZ_BH3)
#define O_ST    (O_P2  + SZ_BH3)
#define O_ROT   (O_ST  + SZ_ST)
#define O_NW    (O_ROT + SZ_ROT)
#define O_CT    (O_NW  + SZ_NH)

// --- K0: cos/sin + nw_g gather table (one thread per (h,l)) --------------
__global__ void k_tab(const float* __restrict__ ang, const float* __restrict__ W_enc,
                      float2* __restrict__ cs, float* __restrict__ gt) {
    int t = blockIdx.x * blockDim.x + threadIdx.x;
    if (t >= HL) return;
    float a = ang[t];
    cs[t] = make_float2(cosf(a), sinf(a));
    int h = t / LL, l = t - LL * (t / LL);
    int n = SS * h + l;
    // band of row n: [ended, hhi]; ct==1 throughout (proved: valid mask == ct mask)
    int ended = (n >= LL) ? (n - SS) / SS : 0;           // ceil((n-19)/10)
    int hhi = n / SS; if (hhi > HH - 1) hhi = HH - 1;
    float denom = 0.f;
    for (int hp = ended; hp <= hhi; ++hp)
        denom += W_enc[(size_t)((n - SS * hp) * HH + hp) * 3];
    gt[t] = W_enc[(size_t)(l * HH + h) * 3] / denom;
}

// --- K1: band fill of nw / ct (arrays pre-memset to 0); one thread per i -
__global__ void k_band(const float* __restrict__ W_enc,
                       float* __restrict__ nw, float* __restrict__ ct) {
    int i = blockIdx.x * blockDim.x + threadIdx.x;
    if (i >= NN) return;
    int ended = (i >= LL) ? (i - SS) / SS : 0;
    int hhi = i / SS; if (hhi > HH - 1) hhi = HH - 1;
    float denom = 0.f;
    for (int hp = ended; hp <= hhi; ++hp)
        denom += W_enc[(size_t)((i - SS * hp) * HH + hp) * 3];
    size_t row = (size_t)i * HH;
    for (int h = ended; h <= hhi; ++h) {
        ct[row + h] = 1.0f;
        nw[row + h] = W_enc[(size_t)((i - SS * h) * HH + h) * 3] / denom;
    }
}

// --- K2: main per-(b, h-tile) block kernel -------------------------------
__global__ void __launch_bounds__(TPB) k_main(
    const float*  __restrict__ x,       const float* __restrict__ W_enc,
    const float*  __restrict__ W_dec,   const float* __restrict__ ang,
    const float2* __restrict__ cs_tab,  const float* __restrict__ g_tab,
    const float*  __restrict__ scaling, const float* __restrict__ nw,
    float* __restrict__ recon, float* __restrict__ Pout,
    float* __restrict__ p1out, float* __restrict__ p2out,
    float* __restrict__ stout, float* __restrict__ rotout) {

    __shared__ float xs[(SS*TPB + SS) * 3];   // 7710 floats
    __shared__ float rb[(SS*TPB + SS) * 3];   // 7710 floats

    int tile = blockIdx.x & (NT - 1);
    int b    = blockIdx.x >> 2;
    int h0   = tile * TPB;
    int cnt  = HH - h0; if (cnt > TPB) cnt = TPB;
    int t    = threadIdx.x;
    int a0   = SS * h0;
    int nf   = (SS * cnt + SS) * 3;

    // stage x window (coalesced)
    const float* xsrc = x + ((size_t)b * NN + a0) * 3;
    for (int j = t; j < nf; j += TPB) xs[j] = xsrc[j];
    __syncthreads();

    // st writes: fully coalesced contiguous dword stores per i
    for (int i = 0; i < LL; ++i) {
        float* dst = stout + (((size_t)b * LL + i) * HH + h0) * 3;
        for (int j = t; j < cnt * 3; j += TPB) {
            int hh = j / 3, k = j - 3 * hh;
            dst[j] = xs[(SS * hh + i) * 3 + k];
        }
    }

    int h = h0 + t;
    float Px=0,Py=0,Pz=0, p1x=0,p1y=0,p1z=0, p2x=0,p2y=0,p2z=0;
    float ra[3 * LL];

    if (t < cnt) {
        float e00=0,e01=0,e02=0, e10=0,e11=0,e12=0, e20=0,e21=0,e22=0;
        const float* xl = xs + (size_t)SS * t * 3;
#pragma unroll
        for (int i = 0; i < LL; ++i) {
            float v0 = xl[i*3+0], v1 = xl[i*3+1], v2 = xl[i*3+2];
            const float* we = W_enc + ((size_t)i * HH + h) * 3;
            float w0 = we[0], w1 = we[1], w2 = we[2];
            e00 = fmaf(v0, w0, e00); e01 = fmaf(v1, w0, e01); e02 = fmaf(v2, w0, e02);
            e10 = fmaf(v0, w1, e10); e11 = fmaf(v1, w1, e11); e12 = fmaf(v2, w1, e12);
            e20 = fmaf(v0, w2, e20); e21 = fmaf(v1, w2, e21); e22 = fmaf(v2, w2, e22);
        }
        Px = e00; Py = e01; Pz = e02;
        float d1x = e10-Px, d1y = e11-Py, d1z = e12-Pz;
        float d2x = e20-Px, d2y = e21-Py, d2z = e22-Pz;
        float n1 = sqrtf(d1x*d1x + d1y*d1y + d1z*d1z); if (n1 == 0.f) n1 = 1.f;
        float n2 = sqrtf(d2x*d2x + d2y*d2y + d2z*d2z); if (n2 == 0.f) n2 = 1.f;
        p1x = d1x/n1; p1y = d1y/n1; p1z = d1z/n1;
        p2x = d2x/n2; p2y = d2y/n2; p2z = d2z/n2;
        float cx = (p1y*p2z - p1z*p2y) * INV_SQRT6;
        float cy = (p1z*p2x - p1x*p2z) * INV_SQRT6;
        float cz = (p1x*p2y - p1y*p2x) * INV_SQRT6;

        size_t bh = (size_t)b * HH + h;
        Pout [bh*3+0]=Px;  Pout [bh*3+1]=Py;  Pout [bh*3+2]=Pz;
        p1out[bh*3+0]=p1x; p1out[bh*3+1]=p1y; p1out[bh*3+2]=p1z;
        p2out[bh*3+0]=p2x; p2out[bh*3+1]=p2y; p2out[bh*3+2]=p2z;

        const float* wd0 = W_dec + (size_t)h * LL;
        const float* wd1 = wd0 + (size_t)HH * LL;
        const float* wd2 = wd1 + (size_t)HH * LL;
#pragma unroll
        for (int l = 0; l < LL; ++l) {
            float w0 = wd0[l], w1 = wd1[l], w2 = wd2[l];
            ra[l*3+0] = p1x*w0 + p2x*w1 + cx*w2;
            ra[l*3+1] = p1y*w0 + p2y*w1 + cy*w2;
            ra[l*3+2] = p1z*w0 + p2z*w1 + cz*w2;
        }
        float4* ro4 = (float4*)(rotout + bh * (size_t)(LL*3));
#pragma unroll
        for (int q = 0; q < (3*LL)/4; ++q)
            ro4[q] = make_float4(ra[4*q+0], ra[4*q+1], ra[4*q+2], ra[4*q+3]);
    }

    // recon contribution for (h, l) -> c3[3]
    auto contrib = [&](int l, float* c3) {
        float r0 = ra[l*3+0], r1 = ra[l*3+1], r2 = ra[l*3+2];
        float ca, sa, g;
        if (cs_tab) {
            float2 c2 = cs_tab[h*LL + l]; ca = c2.x; sa = c2.y;
            g = g_tab[h*LL + l];
        } else {
            float a = ang[h*LL + l]; ca = cosf(a); sa = sinf(a);
            g = nw[(size_t)(SS*h + l) * HH + h];
        }
        float qx = sa*r0, qy = sa*r1, qz = sa*r2;
        float tt = ca*ca - (qx*qx + qy*qy + qz*qz);
        float rv = qx*p1x + qy*p1y + qz*p1z;
        float axv = qy*p1z - qz*p1y;
        float ayv = qz*p1x - qx*p1z;
        float azv = qx*p1y - qy*p1x;
        float sc = scaling[SS*h + l];
        c3[0] = (sc * (tt*p1x + 2.f*(rv*qx + ca*axv)) + Px) * g;
        c3[1] = (sc * (tt*p1y + 2.f*(rv*qy + ca*ayv)) + Py) * g;
        c3[2] = (sc * (tt*p1z + 2.f*(rv*qz + ca*azv)) + Pz) * g;
    };

    // phase A: low halves (and high half for the last thread) -> LDS write
    if (t < cnt) {
        for (int l = 0; l < SS; ++l) {
            float c3[3]; contrib(l, c3);
            rb[30*t + 3*l + 0] = c3[0];
            rb[30*t + 3*l + 1] = c3[1];
            rb[30*t + 3*l + 2] = c3[2];
        }
        if (t == cnt - 1) {
            for (int l = SS; l < LL; ++l) {
                float c3[3]; contrib(l, c3);
                rb[30*t + 3*l + 0] = c3[0];
                rb[30*t + 3*l + 1] = c3[1];
                rb[30*t + 3*l + 2] = c3[2];
            }
        }
    }
    __syncthreads();
    // phase B: high halves accumulate into neighbor's slots
    if (t < cnt - 1) {
        for (int l = SS; l < LL; ++l) {
            float c3[3]; contrib(l, c3);
            rb[30*t + 3*l + 0] += c3[0];
            rb[30*t + 3*l + 1] += c3[1];
            rb[30*t + 3*l + 2] += c3[2];
        }
    }
    __syncthreads();

    // interior atoms: plain coalesced store; 2x10 boundary atoms: atomicAdd
    float* rdst = recon + ((size_t)b * NN + a0) * 3;
    int interiorEnd = 30 * cnt;
    for (int j = 30 + t; j < interiorEnd; j += TPB) rdst[j] = rb[j];
    if (t < 30) atomicAdd(rdst + t, rb[t]);
    if (t >= 64 && t < 94) {
        int j = interiorEnd + (t - 64);
        atomicAdd(rdst + j, rb[j]);
    }
}

extern "C" void kernel_launch(void* const* d_in, const int* in_sizes, int n_in,
                              void* d_out, int out_size, void* d_ws, size_t ws_size,
                              hipStream_t stream) {
    const float* x       = (const float*)d_in[0];
    const float* W_enc   = (const float*)d_in[1];
    const float* W_dec   = (const float*)d_in[2];
    const float* ang     = (const float*)d_in[3];
    const float* scaling = (const float*)d_in[4];
    float* out = (float*)d_out;

    float2* cs = nullptr; float* gt = nullptr;
    size_t need = (size_t)HL * (sizeof(float2) + sizeof(float));
    if (ws_size >= need) {
        cs = (float2*)d_ws;
        gt = (float*)(cs + HL);
    }

    // zero recon (atomic/accumulate base) and the nw/ct region (sparse band)
    hipMemsetAsync(out + O_REC, 0, (size_t)SZ_REC * sizeof(float), stream);
    hipMemsetAsync(out + O_NW, 0, (size_t)(2 * SZ_NH) * sizeof(float), stream);

    if (cs) k_tab<<<(HL + 255)/256, 256, 0, stream>>>(ang, W_enc, cs, gt);
    k_band<<<(NN + 255)/256, 256, 0, stream>>>(W_enc, out + O_NW, out + O_CT);

    k_main<<<BB * NT, TPB, 0, stream>>>(
        x, W_enc, W_dec, ang, cs, gt, scaling, out + O_NW,
        out + O_REC, out + O_P, out + O_P1, out + O_P2, out + O_ST, out + O_ROT);
}